// Round 3
// baseline (502.942 us; speedup 1.0000x reference)
//
#include <hip/hip_runtime.h>

#define TILE 16
#define RR 8
#define ND 17          // 2r+1 displacements per axis
#define HH 512
#define WW 512
#define CC 3
#define BB 4
#define WROWS 32       // window rows/cols in LDS
#define WSTR 36        // window LDS row stride
#define SSTR 20        // src LDS row stride
#define BLK 256        // 4 waves; wave w: one quad-pass dy={w,w+4,w+8,w+12}, wave0 also dy=16

typedef float f4a __attribute__((ext_vector_type(4), aligned(4)));
typedef unsigned long long u64;

// x += lane(l+N) within 16-lane DPP row (row_shl:N, VALU pipe, 0 shifted in).
// Sums complete at lane 0 of each row (empirically validated orientation, R1/R2).
template <int N>
__device__ __forceinline__ float shl_add(float x) {
    return x + __int_as_float(
        __builtin_amdgcn_update_dpp(0, __float_as_int(x), 0x100 + N, 0xF, 0xF, true));
}

// One quad-pass: lane (q=l>>4, i=l&15) computes the full row-SAD for its dy,
// output row i, all 17 dx in-register. Summation tree is BIT-IDENTICAL to R2:
//   accA = sum_{c serial} sum_{j=0..7 serial},  accB = same for j=8..15
//   x = accA + accB                      (== R2's xor2 jg-combine)
//   shl1,shl2,shl4,shl8 adjacent-pair tree over i (== R2's xor4,8,16,32)
// Result key valid at lanes with i==0.
__device__ __forceinline__ u64 sad_quad(const float* Wl, const float* Sl,
                                        int dy, int i) {
    float accA[17], accB[17];
    #pragma unroll
    for (int a = 0; a < 17; ++a) { accA[a] = 0.f; accB[a] = 0.f; }
    const int R = dy + i;
    #pragma unroll
    for (int c = 0; c < CC; ++c) {
        const float* wr = &Wl[c * (WROWS * WSTR) + R * WSTR];
        const float* sr = &Sl[c * (TILE * SSTR) + i * SSTR];
        f4a w0 = *(const f4a*)&wr[0],  w1 = *(const f4a*)&wr[4],
            w2 = *(const f4a*)&wr[8],  w3 = *(const f4a*)&wr[12],
            w4 = *(const f4a*)&wr[16], w5 = *(const f4a*)&wr[20],
            w6 = *(const f4a*)&wr[24], w7 = *(const f4a*)&wr[28];
        f4a s0 = *(const f4a*)&sr[0], s1 = *(const f4a*)&sr[4],
            s2 = *(const f4a*)&sr[8], s3 = *(const f4a*)&sr[12];
        float W32[32] = { w0.x,w0.y,w0.z,w0.w, w1.x,w1.y,w1.z,w1.w,
                          w2.x,w2.y,w2.z,w2.w, w3.x,w3.y,w3.z,w3.w,
                          w4.x,w4.y,w4.z,w4.w, w5.x,w5.y,w5.z,w5.w,
                          w6.x,w6.y,w6.z,w6.w, w7.x,w7.y,w7.z,w7.w };
        float S16[16] = { s0.x,s0.y,s0.z,s0.w, s1.x,s1.y,s1.z,s1.w,
                          s2.x,s2.y,s2.z,s2.w, s3.x,s3.y,s3.z,s3.w };
        #pragma unroll
        for (int a = 0; a < 17; ++a) {
            float tA = accA[a], tB = accB[a];
            #pragma unroll
            for (int j = 0; j < 8; ++j)  tA += fabsf(W32[a + j] - S16[j]);
            #pragma unroll
            for (int j = 8; j < 16; ++j) tB += fabsf(W32[a + j] - S16[j]);
            accA[a] = tA; accB[a] = tB;
        }
    }
    // i-tree reduce (pure VALU DPP) + argmin over dx ascending, strict <
    float bc = 0.f; int ba = 0;
    #pragma unroll
    for (int a = 0; a < 17; ++a) {
        float x = accA[a] + accB[a];
        x = shl_add<1>(x);
        x = shl_add<2>(x);
        x = shl_add<4>(x);
        x = shl_add<8>(x);
        if (a == 0 || x < bc) { bc = x; ba = a; }
    }
    return ((u64)__float_as_uint(bc) << 32) | (unsigned)(dy * ND + ba);
}

__global__ __launch_bounds__(BLK, 4) void tile_kernel(const float* __restrict__ src,
                                                      const float* __restrict__ dst,
                                                      const int* __restrict__ offset,
                                                      float* __restrict__ out) {
    __shared__ float Wl[CC * WROWS * WSTR];   // 13824 B
    __shared__ float Sl[CC * TILE * SSTR];    //  3840 B
    __shared__ u64   keyW[16];

    const int bid  = blockIdx.x;
    const int tile = ((bid & 7) << 9) | (bid >> 3);  // XCD-banding swizzle
    const int b  = tile >> 10;
    const int th = (tile >> 5) & 31;
    const int tw = tile & 31;
    const int ti = th * TILE, tj = tw * TILE;
    const int oy = offset[(b * 2 + 0) * 1024 + th * 32 + tw];
    const int ox = offset[(b * 2 + 1) * 1024 + th * 32 + tw];
    const int t  = threadIdx.x;

    // ---- stage 3x32x32 dst window (zero-padded) coalesced into LDS ----
    const int gy0 = ti + oy - RR;
    const int gx0 = tj + ox - RR;
    for (int k = t; k < CC * WROWS * 8; k += BLK) {   // 768 float4 chunks, 3 iters
        int c   = k >> 8;
        int rem = k & 255;
        int row = rem >> 3;
        int cc  = (rem & 7) << 2;
        int gy = gy0 + row;
        int gx = gx0 + cc;
        float4 v = make_float4(0.f, 0.f, 0.f, 0.f);
        if ((unsigned)gy < HH) {
            const float* p = dst + ((size_t)(b * CC + c) * HH + gy) * WW;
            if ((unsigned)gx <= WW - 4) {
                f4a u = *(const f4a*)(p + gx);
                v = make_float4(u.x, u.y, u.z, u.w);
            } else {
                float* ve = (float*)&v;
                #pragma unroll
                for (int e = 0; e < 4; ++e) {
                    int g = gx + e;
                    if ((unsigned)g < WW) ve[e] = p[g];
                }
            }
        }
        *(f4a*)&Wl[c * (WROWS * WSTR) + row * WSTR + cc] = *(f4a*)&v;
    }
    // ---- stage 3x16x16 src tile (always in-bounds, aligned) ----
    if (t < 192) {
        int k   = t;                       // 192 float4 chunks
        int c   = k >> 6;
        int rem = k & 63;
        int row = rem >> 2;
        int cc  = (rem & 3) << 2;
        f4a v = *(const f4a*)(src + ((size_t)(b * CC + c) * HH + ti + row) * WW + tj + cc);
        *(f4a*)&Sl[c * (TILE * SSTR) + row * SSTR + cc] = v;
    }
    __syncthreads();

    // lane map: q = dy-slot (bits 4-5), i = output row (bits 0-3)
    const int wv = t >> 6;
    const int l  = t & 63;
    const int q  = (l >> 4) & 3;
    const int i  = l & 15;

    // wave wv: pass 0 covers dy = wv + 4q (dy 0..15 across block);
    // wave 0 runs a second pass with dy = 16 (all q redundant; min is idempotent)
    const int npass = (wv == 0) ? 2 : 1;
    u64 bestkey = ~0ull;
    for (int p = 0; p < npass; ++p) {
        const int dy = (p == 0) ? (wv + 4 * q) : 16;
        u64 k = sad_quad(Wl, Sl, dy, i);
        if (k < bestkey) bestkey = k;
    }
    if (i == 0) keyW[wv * 4 + q] = bestkey;
    __syncthreads();

    // block-wide winner (u64 min; d in low bits gives exact smallest-d ties)
    u64 wk = keyW[0];
    #pragma unroll
    for (int w = 1; w < 16; ++w) { u64 kw = keyW[w]; if (kw < wk) wk = kw; }
    const int d   = (int)(wk & 0xFFFFFFFFu);
    const int bdy = d / ND;
    const int bdx = d - bdy * ND;

    if (t == 0) out[(b * 2 + 0) * 1024 + th * 32 + tw] = (float)(oy + bdy - RR);
    if (t == 1) out[(b * 2 + 1) * 1024 + th * 32 + tw] = (float)(ox + bdx - RR);

    // aligned tile is already in the LDS window; nontemporal dwordx4 stores
    // (write-once data — don't allocate in L2, avoid partial-line RMW churn)
    float* aligned = out + BB * 2 * 1024;
    if (t < 192) {
        const int c   = t >> 6;
        const int rem = t & 63;
        const int ii  = rem >> 2;
        const int jj4 = (rem & 3) << 2;
        const float* wp = &Wl[c * (WROWS * WSTR) + (bdy + ii) * WSTR + bdx + jj4];
        f4a v;
        v.x = wp[0]; v.y = wp[1]; v.z = wp[2]; v.w = wp[3];
        __builtin_nontemporal_store(
            v, (f4a*)&aligned[((size_t)(b * CC + c) * HH + ti + ii) * WW + tj + jj4]);
    }
}

extern "C" void kernel_launch(void* const* d_in, const int* in_sizes, int n_in,
                              void* d_out, int out_size, void* d_ws, size_t ws_size,
                              hipStream_t stream) {
    const float* src    = (const float*)d_in[0];
    const float* dst    = (const float*)d_in[1];
    const int*   offset = (const int*)d_in[2];
    float*       out    = (float*)d_out;
    tile_kernel<<<dim3(BB * 1024), BLK, 0, stream>>>(src, dst, offset, out);
}

// Round 4
// 120.884 us; speedup vs baseline: 4.1605x; 4.1605x over previous
//
#include <hip/hip_runtime.h>

#define TILE 16
#define RR 8
#define ND 17          // 2r+1 displacements per axis
#define HH 512
#define WW 512
#define CC 3
#define BB 4
#define WROWS 32       // window rows/cols in LDS
#define WSTR 36        // window LDS row stride
#define SSTR 20        // src LDS row stride
#define BLK 256        // 4 waves; wave w covers dy = w, w+4, w+8, w+12 (+16 for w0)

typedef float f4a __attribute__((ext_vector_type(4), aligned(4)));
typedef unsigned long long u64;

// x += lane(l+N) within 16-lane DPP row (row_shl:N, VALU pipe, 0 shifted in).
// Parity classes (bit0) preserved for even N.
template <int N>
__device__ __forceinline__ float shl_add(float x) {
    return x + __int_as_float(
        __builtin_amdgcn_update_dpp(0, __float_as_int(x), 0x100 + N, 0xF, 0xF, true));
}
// x + lane(l^16) via v_permlane16_swap_b32 (VALU pipe, gfx950):
// swaps dst rows 1,3 with src rows 0,2; with dst=src=x, A+B = x + x[l^16].
__device__ __forceinline__ float swap16_add(float x) {
    float a = x, b = x;
    asm("v_permlane16_swap_b32 %0, %1" : "+&v"(a), "+&v"(b));
    return a + b;
}
// x + lane(l^32) via v_permlane32_swap_b32 (VALU pipe, gfx950):
// swaps dst rows 2,3 with src rows 0,1; with dst=src=x, A+B = x + x[l^32].
__device__ __forceinline__ float swap32_add(float x) {
    float a = x, b = x;
    asm("v_permlane32_swap_b32 %0, %1" : "+&v"(a), "+&v"(b));
    return a + b;
}
// min(k, key at lane^1) via DPP quad_perm(1,0,3,2) on both u64 halves (VALU).
__device__ __forceinline__ u64 xor1_min(u64 k) {
    unsigned lo = (unsigned)k, hi = (unsigned)(k >> 32);
    unsigned olo = (unsigned)__builtin_amdgcn_update_dpp(0, (int)lo, 0xB1, 0xF, 0xF, true);
    unsigned ohi = (unsigned)__builtin_amdgcn_update_dpp(0, (int)hi, 0xB1, 0xF, 0xF, true);
    u64 ok = ((u64)ohi << 32) | olo;
    return ok < k ? ok : k;
}

// one dy-pass: SAD over the LDS window, reduce (VALU-only cross-lane),
// per-lane-pair argmin -> key. Result valid in lane 0.
__device__ __forceinline__ u64 sad_pass(const float* Wl, const float S[CC][8],
                                        int dy, int i, int h, int jg) {
    float acc[9];
    #pragma unroll
    for (int a = 0; a < 9; ++a) acc[a] = 0.f;
    #pragma unroll
    for (int c = 0; c < CC; ++c) {
        const int wb = c * (WROWS * WSTR) + (dy + i) * WSTR + 8 * (h + jg);
        f4a a0 = *(const f4a*)&Wl[wb + 0];
        f4a a1 = *(const f4a*)&Wl[wb + 4];
        f4a a2 = *(const f4a*)&Wl[wb + 8];
        f4a a3 = *(const f4a*)&Wl[wb + 12];
        float W16[16] = { a0.x, a0.y, a0.z, a0.w, a1.x, a1.y, a1.z, a1.w,
                          a2.x, a2.y, a2.z, a2.w, a3.x, a3.y, a3.z, a3.w };
        #pragma unroll
        for (int a = 0; a < 9; ++a) {
            float s0 = acc[a];
            #pragma unroll
            for (int jl = 0; jl < 8; ++jl)
                s0 += fabsf(W16[a + jl] - S[c][jl]);
            acc[a] = s0;
        }
    }
    // reduce over lane bits 1..5 (jg, i); bit0 (h) preserved. All VALU pipe:
    // DPP row_shl for bits 1-3, permlane16/32_swap for bits 4-5.
    // Sums complete in lanes 0 (h=0) and 1 (h=1); higher lanes never consumed.
    #pragma unroll
    for (int a = 0; a < 9; ++a) {
        float x = acc[a];
        x = shl_add<2>(x);        // + lane+2   (bit1)
        x = shl_add<4>(x);        // + lanes+4,+6 (bit2)
        x = shl_add<8>(x);        // + lanes+8..+14 (bit3)
        x = swap16_add(x);        // xor16 (bit4)
        x = swap32_add(x);        // xor32 (bit5)
        acc[a] = x;
    }
    // per-lane argmin over this h-group's dx (h=1 skips a=0: dx=8 dup);
    // ascending a + strict < keeps the smallest dx on ties.
    float bc = h ? acc[1] : acc[0];
    int   ba = h;
    #pragma unroll
    for (int a = 1; a < 9; ++a)
        if (a > h && acc[a] < bc) { bc = acc[a]; ba = a; }
    const unsigned d = (unsigned)(dy * ND + 8 * h + ba);
    u64 key = ((u64)__float_as_uint(bc) << 32) | d;   // cost>=0: bit order = numeric
    return xor1_min(key);                              // valid in lane 0
}

__global__ __launch_bounds__(BLK, 8) void tile_kernel(const float* __restrict__ src,
                                                      const float* __restrict__ dst,
                                                      const int* __restrict__ offset,
                                                      float* __restrict__ out) {
    __shared__ float Wl[CC * WROWS * WSTR];   // 13824 B
    __shared__ float Sl[CC * TILE * SSTR];    //  3840 B
    __shared__ u64   keyL[4];

    const int bid  = blockIdx.x;
    const int tile = ((bid & 7) << 9) | (bid >> 3);  // XCD-banding swizzle
    const int b  = tile >> 10;
    const int th = (tile >> 5) & 31;
    const int tw = tile & 31;
    const int ti = th * TILE, tj = tw * TILE;
    const int oy = offset[(b * 2 + 0) * 1024 + th * 32 + tw];
    const int ox = offset[(b * 2 + 1) * 1024 + th * 32 + tw];
    const int t  = threadIdx.x;

    // ---- stage 3x32x32 dst window (zero-padded) coalesced into LDS ----
    const int gy0 = ti + oy - RR;
    const int gx0 = tj + ox - RR;
    for (int k = t; k < CC * WROWS * 8; k += BLK) {   // 768 float4 chunks, 3 iters
        int c   = k >> 8;
        int rem = k & 255;
        int row = rem >> 3;
        int cc  = (rem & 7) << 2;
        int gy = gy0 + row;
        int gx = gx0 + cc;
        float4 v = make_float4(0.f, 0.f, 0.f, 0.f);
        if ((unsigned)gy < HH) {
            const float* p = dst + ((size_t)(b * CC + c) * HH + gy) * WW;
            if ((unsigned)gx <= WW - 4) {
                f4a u = *(const f4a*)(p + gx);
                v = make_float4(u.x, u.y, u.z, u.w);
            } else {
                float* ve = (float*)&v;
                #pragma unroll
                for (int e = 0; e < 4; ++e) {
                    int g = gx + e;
                    if ((unsigned)g < WW) ve[e] = p[g];
                }
            }
        }
        *(f4a*)&Wl[c * (WROWS * WSTR) + row * WSTR + cc] = *(f4a*)&v;
    }
    // ---- stage 3x16x16 src tile (always in-bounds, aligned) ----
    if (t < 192) {
        int k   = t;                       // 192 float4 chunks
        int c   = k >> 6;
        int rem = k & 63;
        int row = rem >> 2;
        int cc  = (rem & 3) << 2;
        f4a v = *(const f4a*)(src + ((size_t)(b * CC + c) * HH + ti + row) * WW + tj + cc);
        *(f4a*)&Sl[c * (TILE * SSTR) + row * SSTR + cc] = v;
    }
    __syncthreads();

    // lane map: h=bit0 (dx 0..8 / 8..16), jg=bit1 (j half), i=bits2..5 (row)
    const int wv = t >> 6;
    const int l  = t & 63;
    const int h  = l & 1;
    const int jg = (l >> 1) & 1;
    const int i  = l >> 2;

    float S[CC][8];
    #pragma unroll
    for (int c = 0; c < CC; ++c) {
        const int sb = c * (TILE * SSTR) + i * SSTR + 8 * jg;
        f4a s0 = *(const f4a*)&Sl[sb];
        f4a s1 = *(const f4a*)&Sl[sb + 4];
        S[c][0]=s0.x; S[c][1]=s0.y; S[c][2]=s0.z; S[c][3]=s0.w;
        S[c][4]=s1.x; S[c][5]=s1.y; S[c][6]=s1.z; S[c][7]=s1.w;
    }

    // wave wv covers dy = wv, wv+4, wv+8, wv+12 (all < 16), wave 0 also dy=16
    u64 bestkey = sad_pass(Wl, S, wv, i, h, jg);
    #pragma unroll
    for (int p = 1; p < 4; ++p) {
        u64 k2 = sad_pass(Wl, S, wv + 4 * p, i, h, jg);
        if (k2 < bestkey) bestkey = k2;
    }
    if (wv == 0) {
        u64 k2 = sad_pass(Wl, S, 16, i, h, jg);
        if (k2 < bestkey) bestkey = k2;
    }
    if (l == 0) keyL[wv] = bestkey;
    __syncthreads();

    // block-wide winner (u64 min; d in low bits gives exact smallest-d ties)
    u64 wk = keyL[0];
    #pragma unroll
    for (int w = 1; w < 4; ++w) { u64 kw = keyL[w]; if (kw < wk) wk = kw; }
    const int d   = (int)(wk & 0xFFFFFFFFu);
    const int bdy = d / ND;
    const int bdx = d - bdy * ND;

    if (t == 0) out[(b * 2 + 0) * 1024 + th * 32 + tw] = (float)(oy + bdy - RR);
    if (t == 1) out[(b * 2 + 1) * 1024 + th * 32 + tw] = (float)(ox + bdx - RR);

    // aligned tile is already in the LDS window; dwordx4 coalesced stores
    float* aligned = out + BB * 2 * 1024;
    if (t < 192) {
        const int c   = t >> 6;
        const int rem = t & 63;
        const int ii  = rem >> 2;
        const int jj4 = (rem & 3) << 2;
        const float* wp = &Wl[c * (WROWS * WSTR) + (bdy + ii) * WSTR + bdx + jj4];
        float4 v = make_float4(wp[0], wp[1], wp[2], wp[3]);
        *(f4a*)&aligned[((size_t)(b * CC + c) * HH + ti + ii) * WW + tj + jj4] =
            *(f4a*)&v;
    }
}

extern "C" void kernel_launch(void* const* d_in, const int* in_sizes, int n_in,
                              void* d_out, int out_size, void* d_ws, size_t ws_size,
                              hipStream_t stream) {
    const float* src    = (const float*)d_in[0];
    const float* dst    = (const float*)d_in[1];
    const int*   offset = (const int*)d_in[2];
    float*       out    = (float*)d_out;
    tile_kernel<<<dim3(BB * 1024), BLK, 0, stream>>>(src, dst, offset, out);
}